// Round 12
// baseline (173.537 us; speedup 1.0000x reference)
//
#include <hip/hip_runtime.h>
#include <stdint.h>

typedef unsigned int u32;
typedef unsigned short u16;
typedef unsigned long long u64;
typedef __bf16 bf16x8 __attribute__((ext_vector_type(8)));
typedef float f32x4 __attribute__((ext_vector_type(4)));
typedef u32 u32x4 __attribute__((ext_vector_type(4)));

#define IN_DIM 512

__device__ __forceinline__ u16 bfr(float f) {
  __bf16 h = (__bf16)f;
  return __builtin_bit_cast(u16, h);
}
__device__ __forceinline__ u16 f2bf(float f) {
  u32 u = __builtin_bit_cast(u32, f);
  u += 0x7fffu + ((u >> 16) & 1u);
  return (u16)(u >> 16);
}
__device__ __forceinline__ u32 pk2(float a, float b) {
  return (u32)f2bf(a) | ((u32)f2bf(b) << 16);
}

// ---------------------------------------------------------------------------
// pack_b: B packed in MFMA-fragment order (L2->VGPR direct in the GEMM).
// Chunk(nbp, s, cb, ks) = 64 lanes x 16B; lane l holds
//   col = nbp*128 + cb*16 + (l&15), kexp = s*64 + ks*32 + (l>>4)*8 .. +7
// Per (col,dim) 16 slots: 0..12 coeffs, 13=W, 14=W, 15=0.
// ---------------------------------------------------------------------------
__global__ void pack_b(const float* __restrict__ coeffs,
                       const float* __restrict__ bw,
                       char* __restrict__ Bp) {
  __shared__ float stage[64][56];
  const int tid = threadIdx.x;
  const int q = tid & 3, g = tid >> 2;
  const int id = blockIdx.x * 64 + g;          // (col, s) pair
  const int col = id >> 7, s = id & 127;
  const float* cbase = coeffs + ((size_t)col * IN_DIM + s * 4) * 13;
#pragma unroll
  for (int j = 0; j < 3; ++j) {
    int ch = q + j * 4;
    float4 v = *(const float4*)(cbase + ch * 4);
    stage[g][ch * 4 + 0] = v.x; stage[g][ch * 4 + 1] = v.y;
    stage[g][ch * 4 + 2] = v.z; stage[g][ch * 4 + 3] = v.w;
  }
  if (q == 0) {
    float4 v = *(const float4*)(cbase + 48);
    stage[g][48] = v.x; stage[g][49] = v.y; stage[g][50] = v.z; stage[g][51] = v.w;
  }
  if (q == 1) {
    float4 v = *(const float4*)(bw + (size_t)col * IN_DIM + s * 4);
    stage[g][52] = v.x; stage[g][53] = v.y; stage[g][54] = v.z; stage[g][55] = v.w;
  }
  __syncthreads();
  const int nbp = col >> 7, cb = (col >> 4) & 7, cl = col & 15;
  char* base = Bp + (((size_t)(nbp * 128 + s) * 8 + cb) * 2) * 1024;
#pragma unroll
  for (int r = 0; r < 2; ++r) {
    int idx = q * 2 + r;
    int h = idx & 1;
    int dd = idx >> 1;              // dim-in-step 0..3
    int ks = dd >> 1;
    const float* sf = &stage[g][dd * 13];
    float w = stage[g][52 + dd];
    u16 hh[8];
#pragma unroll
    for (int c = 0; c < 8; ++c) {
      int slot = h * 8 + c;
      float v = slot < 13 ? sf[slot] : (slot < 15 ? w : 0.0f);
      hh[c] = bfr(v);
    }
    u32x4 o;
    o.x = (u32)hh[0] | ((u32)hh[1] << 16);
    o.y = (u32)hh[2] | ((u32)hh[3] << 16);
    o.z = (u32)hh[4] | ((u32)hh[5] << 16);
    o.w = (u32)hh[6] | ((u32)hh[7] << 16);
    int lanei = cl + 16 * (2 * (dd & 1) + h);
    *(u32x4*)(base + (size_t)ks * 1024 + lanei * 16) = o;
  }
}

// ---------------------------------------------------------------------------
// expandHalf: one x -> the 8 bf16 K-slots this lane needs (half h of the
// 16-slot expansion). Bit-identical math to the verified LDS expandA path:
// slots jl+2..jl+5 = cubic bases, 13/14 = silu hi/lo, rest 0.
// h=0 -> slots 0..7 (= q0,q1), h=1 -> slots 8..15 (= q2,q3).
// ---------------------------------------------------------------------------
__device__ __forceinline__ u32x4 expandHalf(float xv, int h) {
  float xc = fminf(fmaxf(xv, -0.9999f), 0.9999f);
  float tp = __fmaf_rn(xc, 2.5f, 3.0f);
  float fj = floorf(tp);
  int jl = (int)fj;  // 0..5
  float u = tp - fj;
  float u2 = u * u, u3 = u2 * u;
  float vv = 1.0f - u;
  float b0 = vv * vv * vv * (1.0f / 6.0f);
  float b3 = u3 * (1.0f / 6.0f);
  float b1 = __fmaf_rn(0.5f, u3, __fmaf_rn(u2, -1.0f, 2.0f / 3.0f));
  float b2 = 1.0f - b0 - b1 - b3;
  float e = __expf(-xv);
  float sg = __fdividef(xv, 1.0f + e);
  u16 sh = bfr(sg);
  float shf = __builtin_bit_cast(float, ((u32)sh) << 16);
  u16 sl = bfr(sg - shf);
  u32 pk01 = (u32)bfr(b0) | ((u32)bfr(b1) << 16);
  u32 pk23 = (u32)bfr(b2) | ((u32)bfr(b3) << 16);
  u64 v = (u64)pk01 | (((u64)pk23) << 32);
  int sstart = jl + 2;       // 2..7
  int qa = sstart >> 2;
  int shn = (sstart & 3) << 4;
  u64 lo = v << shn;
  u64 hi = shn ? (v >> (64 - shn)) : 0ull;
  u64 q0 = qa ? 0ull : lo;
  u64 q1 = qa ? lo : hi;
  u64 q2 = qa ? hi : 0ull;
  u64 q3 = (u64)(((u32)sh) << 16) | (((u64)(u32)sl) << 32);
  u64 ra = h ? q2 : q0;
  u64 rb = h ? q3 : q1;
  u32x4 r;
  r.x = (u32)ra; r.y = (u32)(ra >> 32);
  r.z = (u32)rb; r.w = (u32)(rb >> 32);
  return r;
}

// ---------------------------------------------------------------------------
// Main GEMM, ALL-REGISTER A PATH — no LDS, no barriers in the K-loop:
// 8 identical waves (wm2 x wn2 x kt2). Each lane builds its own A-fragments
// in registers from 4 x scalars/step (lane's frag = half(lkg&1) of
// expand(x[row][s*4 + kt*2 + (lkg>>1)]) — identical mapping to the verified
// LDS path). B-frags L2->reg (1-step prefetch, issued BEFORE x loads so
// in-order vmcnt never couples the B-wait to slow x lines). Waves drift
// freely; expansion VALU fills MFMA pipe gaps across waves (m114 overlap).
// LDS only for the epilogue kt-reduction.
// ---------------------------------------------------------------------------
#define MM(AF, BV)                                                             \
  {                                                                            \
    __builtin_amdgcn_s_setprio(1);                                             \
    _Pragma("unroll")                                                          \
    for (int fm = 0; fm < 4; ++fm)                                             \
      _Pragma("unroll")                                                        \
      for (int fn = 0; fn < 4; ++fn)                                           \
        acc[fm][fn] = __builtin_amdgcn_mfma_f32_16x16x32_bf16(                 \
            __builtin_bit_cast(bf16x8, AF[fm]),                                \
            __builtin_bit_cast(bf16x8, BV[fn]), acc[fm][fn], 0, 0, 0);         \
    __builtin_amdgcn_s_setprio(0);                                             \
  }

__launch_bounds__(512, 2)
__global__ void kan_gemm(const float* __restrict__ x,
                         const char* __restrict__ Bp,
                         float* __restrict__ out) {
  __shared__ __align__(16) char smem[67584];  // epilogue red: 128 x 132 f32

  const int tid = threadIdx.x;
  const int lane = tid & 63;
  const int wid = tid >> 6;
  const int kt = wid >> 2;             // K-split team
  const int wm = (wid >> 1) & 1, wn = wid & 1;
  const int lrow = lane & 15, lkg = lane >> 4;
  const int h = lkg & 1;               // which 8-slot half this lane holds
  const int dsel = kt * 2 + (lkg >> 1);  // dim-in-step 0..3

  int s0 = blockIdx.x;
  int xcd = s0 & 7;
  int nb = xcd >> 1;                   // XCD pair owns one 2MB B panel in L2
  int mb = ((s0 >> 3) << 1) | (xcd & 1);  // 0..63

  // per-lane x pointers: row = mb*128 + wm*64 + fm*16 + lrow, col = s*4+dsel
  const float* xp = x + (size_t)(mb * 128 + wm * 64 + lrow) * IN_DIM + dsel;
  // fm stride = 16 rows = 16*512 floats

  const char* bptr = Bp + (((size_t)(nb * 128) * 8 + wn * 4) * 2 + kt) * 1024 + (size_t)lane * 16;

  f32x4 acc[4][4];
#pragma unroll
  for (int i = 0; i < 4; ++i)
#pragma unroll
    for (int j = 0; j < 4; ++j) acc[i][j] = (f32x4){0.f, 0.f, 0.f, 0.f};

  u32x4 bA[4], bB[4], afA[4], afB[4];
  float x1[4], x2[4];

  // prologue: B(0); af(0) from direct x; x1 = x(1), x2 = x(2)
#pragma unroll
  for (int fn = 0; fn < 4; ++fn)
    bA[fn] = *(const u32x4*)(bptr + fn * 2048);
#pragma unroll
  for (int fm = 0; fm < 4; ++fm)
    afA[fm] = expandHalf(xp[(size_t)fm * 16 * IN_DIM], h);
#pragma unroll
  for (int fm = 0; fm < 4; ++fm) x1[fm] = xp[(size_t)fm * 16 * IN_DIM + 4];
#pragma unroll
  for (int fm = 0; fm < 4; ++fm) x2[fm] = xp[(size_t)fm * 16 * IN_DIM + 8];

  // S = current compute step. Loads issued: B(S+1) first, then x(S+3)
  // (B older than x in vmcnt order -> B-wait never drags x). MFMA(S) on
  // regs built last step; then build af(S+1) from x1 (VALU overlaps the
  // MFMA pipe via cross-wave scheduling).
#define STEP(S, AFC, AFN, BCUR, BNXT)                                          \
  {                                                                            \
    int sl_ = (S) + 1 < 128 ? (S) + 1 : 127;                                   \
    _Pragma("unroll")                                                          \
    for (int fn = 0; fn < 4; ++fn)                                             \
      BNXT[fn] = *(const u32x4*)(bptr + (size_t)sl_ * 16384 + fn * 2048);      \
    float xn[4];                                                               \
    int xi = ((S) + 3 < 128 ? (S) + 3 : 127) * 4;                              \
    _Pragma("unroll")                                                          \
    for (int fm = 0; fm < 4; ++fm)                                             \
      xn[fm] = xp[(size_t)fm * 16 * IN_DIM + xi];                              \
    MM(AFC, BCUR)                                                              \
    _Pragma("unroll")                                                          \
    for (int fm = 0; fm < 4; ++fm)                                             \
      AFN[fm] = expandHalf(x1[fm], h);                                         \
    _Pragma("unroll")                                                          \
    for (int fm = 0; fm < 4; ++fm) { x1[fm] = x2[fm]; x2[fm] = xn[fm]; }       \
  }

#pragma unroll 1
  for (int s = 0; s < 128; s += 2) {
    STEP(s, afA, afB, bA, bB)
    STEP(s + 1, afB, afA, bB, bA)
  }

  __syncthreads();  // all waves done computing; smem now safe to use

  // epilogue: deterministic kt-reduction via LDS (stride 132 floats), +x
  float* red = (float*)smem;
  if (kt == 1) {
#pragma unroll
    for (int fm = 0; fm < 4; ++fm)
#pragma unroll
      for (int fn = 0; fn < 4; ++fn) {
        int rr = wm * 64 + fm * 16 + lkg * 4;
        int cc = wn * 64 + fn * 16 + lrow;
#pragma unroll
        for (int r = 0; r < 4; ++r)
          red[(size_t)(rr + r) * 132 + cc] = acc[fm][fn][r];
      }
  }
  __syncthreads();
  if (kt == 0) {
#pragma unroll
    for (int fm = 0; fm < 4; ++fm)
#pragma unroll
      for (int fn = 0; fn < 4; ++fn) {
        int rr = wm * 64 + fm * 16 + lkg * 4;
        int cc = wn * 64 + fn * 16 + lrow;
        size_t gb = (size_t)(mb * 128 + rr) * IN_DIM + nb * 128 + cc;
#pragma unroll
        for (int r = 0; r < 4; ++r) {
          size_t off = gb + (size_t)r * IN_DIM;
          out[off] = acc[fm][fn][r] + red[(size_t)(rr + r) * 132 + cc] + x[off];
        }
      }
  }
}

// ---------------------------------------------------------------------------
// Fallback (round-1 kernel) if ws too small for B_packed (8MB)
// ---------------------------------------------------------------------------
__device__ __forceinline__ void st_b16(char* rb, u32 swz, u32 k0, int c, u16 v) {
  u32 uc = (u32)c;
  u32 byte = (((k0 + (uc >> 3)) ^ swz) << 4) | ((uc & 7u) << 1);
  *(u16*)(rb + byte) = v;
}

__device__ __forceinline__ void stage_a_fb(char* aT, int row, int d, float xv) {
  char* rb = aT + row * 128;
  u32 swz = (u32)(row & 7);
  float xc = fminf(fmaxf(xv, -0.9999f), 0.9999f);
  float tp = __fmaf_rn(xc, 2.5f, 3.0f);
  float fj = floorf(tp);
  int jl = (int)fj;
  float u = tp - fj;
  float u2 = u * u, u3 = u2 * u;
  float vv = 1.0f - u;
  float b0 = vv * vv * vv * (1.0f / 6.0f);
  float b3 = u3 * (1.0f / 6.0f);
  float b1 = __fmaf_rn(0.5f, u3, __fmaf_rn(u2, -1.0f, 2.0f / 3.0f));
  float b2 = 1.0f - b0 - b1 - b3;
  float e = __expf(-xv);
  float sg = __fdividef(xv, 1.0f + e);
  u16 sh = f2bf(sg);
  float shf = __builtin_bit_cast(float, ((u32)sh) << 16);
  u16 slo = f2bf(sg - shf);
  u32 k0 = (u32)d * 2u;
  u32x4 z = {0u, 0u, 0u, 0u};
  *(u32x4*)(rb + ((k0 ^ swz) << 4)) = z;
  u32x4 z2 = {0u, 0u, ((u32)sh) << 16, (u32)slo};
  *(u32x4*)(rb + (((k0 + 1u) ^ swz) << 4)) = z2;
  st_b16(rb, swz, k0, jl + 2, f2bf(b0));
  st_b16(rb, swz, k0, jl + 3, f2bf(b1));
  st_b16(rb, swz, k0, jl + 4, f2bf(b2));
  st_b16(rb, swz, k0, jl + 5, f2bf(b3));
}

__launch_bounds__(512, 2)
__global__ void kan_fused(const float* __restrict__ x,
                          const float* __restrict__ coeffs,
                          const float* __restrict__ bw,
                          float* __restrict__ out) {
  __shared__ __align__(16) char smem[65536];
  const int tid = threadIdx.x;
  const int lane = tid & 63;
  const int wid = tid >> 6;
  const int team = wid >> 2;
  const int wm = (wid >> 1) & 1;
  const int wn = wid & 1;
  const int m0 = wm * 64, n0 = wn * 64;
  const int lrow = lane & 15;
  const int lkg = lane >> 4;
  int s = blockIdx.x;
  int xcd = s & 7;
  int nb = xcd >> 1;
  int mb = (s >> 3) | ((xcd & 1) << 5);
  const int t = tid & 255;
  const int arow = t >> 1;
  const int h = t & 1;
  char* aT = smem + team * 16384;
  char* bT = smem + 32768 + team * 16384;
  const int dim0 = team * 256;
  const float* xptr = x + (size_t)(mb * 128 + arow) * IN_DIM + dim0 + 2 * h;
  const float* cptr = coeffs + ((size_t)((nb * 128 + arow) * IN_DIM) + dim0) * 13 + 26 * h;
  const float* wptr = bw + (size_t)(nb * 128 + arow) * IN_DIM + dim0 + 2 * h;
  f32x4 acc[4][4];
#pragma unroll
  for (int i = 0; i < 4; ++i)
#pragma unroll
    for (int j = 0; j < 4; ++j) acc[i][j] = (f32x4){0.f, 0.f, 0.f, 0.f};
  float2 xv, wv;
  float2 cv0, cv1, cv2, cv3, cv4, cv5, cv6, cv7, cv8, cv9, cv10, cv11, cv12;
#define PREFETCH(STP)                                                     \
  {                                                                       \
    const float* cp_ = cptr + (STP) * 52;                                 \
    xv = *(const float2*)(xptr + (STP) * 4);                              \
    wv = *(const float2*)(wptr + (STP) * 4);                              \
    cv0 = *(const float2*)(cp_ + 0);   cv1 = *(const float2*)(cp_ + 2);   \
    cv2 = *(const float2*)(cp_ + 4);   cv3 = *(const float2*)(cp_ + 6);   \
    cv4 = *(const float2*)(cp_ + 8);   cv5 = *(const float2*)(cp_ + 10);  \
    cv6 = *(const float2*)(cp_ + 12);  cv7 = *(const float2*)(cp_ + 14);  \
    cv8 = *(const float2*)(cp_ + 16);  cv9 = *(const float2*)(cp_ + 18);  \
    cv10 = *(const float2*)(cp_ + 20); cv11 = *(const float2*)(cp_ + 22); \
    cv12 = *(const float2*)(cp_ + 24);                                    \
  }
  PREFETCH(0)
  for (int st = 0; st < 64; ++st) {
    stage_a_fb(aT, arow, 2 * h + 0, xv.x);
    stage_a_fb(aT, arow, 2 * h + 1, xv.y);
    {
      char* rb = bT + arow * 128;
      u32 swz = (u32)(arow & 7);
      u32 k0 = (u32)(2 * h) * 2u;
      u32x4 lo, hi;
      lo.x = pk2(cv0.x, cv0.y); lo.y = pk2(cv1.x, cv1.y);
      lo.z = pk2(cv2.x, cv2.y); lo.w = pk2(cv3.x, cv3.y);
      hi.x = pk2(cv4.x, cv4.y); hi.y = pk2(cv5.x, cv5.y);
      {
        u16 wb = f2bf(wv.x);
        hi.z = (u32)f2bf(cv6.x) | ((u32)wb << 16);
        hi.w = (u32)wb;
      }
      *(u32x4*)(rb + ((k0 ^ swz) << 4)) = lo;
      *(u32x4*)(rb + (((k0 + 1u) ^ swz) << 4)) = hi;
      lo.x = pk2(cv6.y, cv7.x);  lo.y = pk2(cv7.y, cv8.x);
      lo.z = pk2(cv8.y, cv9.x);  lo.w = pk2(cv9.y, cv10.x);
      hi.x = pk2(cv10.y, cv11.x); hi.y = pk2(cv11.y, cv12.x);
      {
        u16 wb = f2bf(wv.y);
        hi.z = (u32)f2bf(cv12.y) | ((u32)wb << 16);
        hi.w = (u32)wb;
      }
      *(u32x4*)(rb + (((k0 + 2u) ^ swz) << 4)) = lo;
      *(u32x4*)(rb + (((k0 + 3u) ^ swz) << 4)) = hi;
    }
    __syncthreads();
    if (st != 63) { PREFETCH(st + 1) }
    {
      const char* arb = aT + (m0 + lrow) * 128;
      const char* brb = bT + (n0 + lrow) * 128;
      u32 rsw = (u32)(lrow & 7);
#pragma unroll
      for (int ks = 0; ks < 2; ++ks) {
        u32 sl2 = (((u32)(ks * 4) | (u32)lkg) ^ rsw) << 4;
        bf16x8 af[4], bfr2[4];
#pragma unroll
        for (int fm = 0; fm < 4; ++fm)
          af[fm] = __builtin_bit_cast(bf16x8, *(const u32x4*)(arb + fm * 2048 + sl2));
#pragma unroll
        for (int fn = 0; fn < 4; ++fn)
          bfr2[fn] = __builtin_bit_cast(bf16x8, *(const u32x4*)(brb + fn * 2048 + sl2));
#pragma unroll
        for (int fm = 0; fm < 4; ++fm)
#pragma unroll
          for (int fn = 0; fn < 4; ++fn)
            acc[fm][fn] = __builtin_amdgcn_mfma_f32_16x16x32_bf16(
                af[fm], bfr2[fn], acc[fm][fn], 0, 0, 0);
      }
    }
    __syncthreads();
  }
  float* red = (float*)smem;
  if (team == 1) {
#pragma unroll
    for (int fm = 0; fm < 4; ++fm)
#pragma unroll
      for (int fn = 0; fn < 4; ++fn) {
        int rr = m0 + fm * 16 + lkg * 4;
        int cc = n0 + fn * 16 + lrow;
#pragma unroll
        for (int r = 0; r < 4; ++r) red[(rr + r) * 128 + cc] = acc[fm][fn][r];
      }
  }
  __syncthreads();
  if (team == 0) {
#pragma unroll
    for (int fm = 0; fm < 4; ++fm)
#pragma unroll
      for (int fn = 0; fn < 4; ++fn) {
        int rr = m0 + fm * 16 + lkg * 4;
        int ccol = n0 + fn * 16 + lrow;
        int grow = mb * 128 + rr;
        int gcol = nb * 128 + ccol;
#pragma unroll
        for (int r = 0; r < 4; ++r) {
          float v = acc[fm][fn][r] + red[(rr + r) * 128 + ccol] +
                    x[(size_t)(grow + r) * IN_DIM + gcol];
          out[(size_t)(grow + r) * IN_DIM + gcol] = v;
        }
      }
  }
}

extern "C" void kernel_launch(void* const* d_in, const int* in_sizes, int n_in,
                              void* d_out, int out_size, void* d_ws, size_t ws_size,
                              hipStream_t stream) {
  const float* x = (const float*)d_in[0];
  const float* coeffs = (const float*)d_in[1];
  const float* bw = (const float*)d_in[2];
  float* out = (float*)d_out;
  if (ws_size >= (size_t)512 * 16384) {  // 8 MB for B_packed
    char* Bp = (char*)d_ws;
    hipLaunchKernelGGL(pack_b, dim3(1024), dim3(256), 0, stream, coeffs, bw, Bp);
    hipLaunchKernelGGL(kan_gemm, dim3(256), dim3(512), 0, stream, x, Bp, out);
  } else {
    hipLaunchKernelGGL(kan_fused, dim3(256), dim3(512), 0, stream, x, coeffs, bw, out);
  }
}

// Round 13
// 126.716 us; speedup vs baseline: 1.3695x; 1.3695x over previous
//
#include <hip/hip_runtime.h>
#include <stdint.h>

typedef unsigned int u32;
typedef unsigned short u16;
typedef unsigned long long u64;
typedef __bf16 bf16x8 __attribute__((ext_vector_type(8)));
typedef float f32x4 __attribute__((ext_vector_type(4)));
typedef u32 u32x4 __attribute__((ext_vector_type(4)));

#define IN_DIM 512

__device__ __forceinline__ u16 bfr(float f) {
  __bf16 h = (__bf16)f;
  return __builtin_bit_cast(u16, h);
}
__device__ __forceinline__ u16 f2bf(float f) {
  u32 u = __builtin_bit_cast(u32, f);
  u += 0x7fffu + ((u >> 16) & 1u);
  return (u16)(u >> 16);
}
__device__ __forceinline__ u32 pk2(float a, float b) {
  return (u32)f2bf(a) | ((u32)f2bf(b) << 16);
}

// ---------------------------------------------------------------------------
// pack_b: B packed in MFMA-fragment order (unchanged, verified).
// ---------------------------------------------------------------------------
__global__ void pack_b(const float* __restrict__ coeffs,
                       const float* __restrict__ bw,
                       char* __restrict__ Bp) {
  __shared__ float stage[64][56];
  const int tid = threadIdx.x;
  const int q = tid & 3, g = tid >> 2;
  const int id = blockIdx.x * 64 + g;          // (col, s) pair
  const int col = id >> 7, s = id & 127;
  const float* cbase = coeffs + ((size_t)col * IN_DIM + s * 4) * 13;
#pragma unroll
  for (int j = 0; j < 3; ++j) {
    int ch = q + j * 4;
    float4 v = *(const float4*)(cbase + ch * 4);
    stage[g][ch * 4 + 0] = v.x; stage[g][ch * 4 + 1] = v.y;
    stage[g][ch * 4 + 2] = v.z; stage[g][ch * 4 + 3] = v.w;
  }
  if (q == 0) {
    float4 v = *(const float4*)(cbase + 48);
    stage[g][48] = v.x; stage[g][49] = v.y; stage[g][50] = v.z; stage[g][51] = v.w;
  }
  if (q == 1) {
    float4 v = *(const float4*)(bw + (size_t)col * IN_DIM + s * 4);
    stage[g][52] = v.x; stage[g][53] = v.y; stage[g][54] = v.z; stage[g][55] = v.w;
  }
  __syncthreads();
  const int nbp = col >> 7, cb = (col >> 4) & 7, cl = col & 15;
  char* base = Bp + (((size_t)(nbp * 128 + s) * 8 + cb) * 2) * 1024;
#pragma unroll
  for (int r = 0; r < 2; ++r) {
    int idx = q * 2 + r;
    int h = idx & 1;
    int dd = idx >> 1;              // dim-in-step 0..3
    int ks = dd >> 1;
    const float* sf = &stage[g][dd * 13];
    float w = stage[g][52 + dd];
    u16 hh[8];
#pragma unroll
    for (int c = 0; c < 8; ++c) {
      int slot = h * 8 + c;
      float v = slot < 13 ? sf[slot] : (slot < 15 ? w : 0.0f);
      hh[c] = bfr(v);
    }
    u32x4 o;
    o.x = (u32)hh[0] | ((u32)hh[1] << 16);
    o.y = (u32)hh[2] | ((u32)hh[3] << 16);
    o.z = (u32)hh[4] | ((u32)hh[5] << 16);
    o.w = (u32)hh[6] | ((u32)hh[7] << 16);
    int lanei = cl + 16 * (2 * (dd & 1) + h);
    *(u32x4*)(base + (size_t)ks * 1024 + lanei * 16) = o;
  }
}

// ---------------------------------------------------------------------------
// expandHalf (verified in R12): one x -> the 8 bf16 K-slots of half h.
// ---------------------------------------------------------------------------
__device__ __forceinline__ u32x4 expandHalf(float xv, int h) {
  float xc = fminf(fmaxf(xv, -0.9999f), 0.9999f);
  float tp = __fmaf_rn(xc, 2.5f, 3.0f);
  float fj = floorf(tp);
  int jl = (int)fj;  // 0..5
  float u = tp - fj;
  float u2 = u * u, u3 = u2 * u;
  float vv = 1.0f - u;
  float b0 = vv * vv * vv * (1.0f / 6.0f);
  float b3 = u3 * (1.0f / 6.0f);
  float b1 = __fmaf_rn(0.5f, u3, __fmaf_rn(u2, -1.0f, 2.0f / 3.0f));
  float b2 = 1.0f - b0 - b1 - b3;
  float e = __expf(-xv);
  float sg = __fdividef(xv, 1.0f + e);
  u16 sh = bfr(sg);
  float shf = __builtin_bit_cast(float, ((u32)sh) << 16);
  u16 sl = bfr(sg - shf);
  u32 pk01 = (u32)bfr(b0) | ((u32)bfr(b1) << 16);
  u32 pk23 = (u32)bfr(b2) | ((u32)bfr(b3) << 16);
  u64 v = (u64)pk01 | (((u64)pk23) << 32);
  int sstart = jl + 2;       // 2..7
  int qa = sstart >> 2;
  int shn = (sstart & 3) << 4;
  u64 lo = v << shn;
  u64 hi = shn ? (v >> (64 - shn)) : 0ull;
  u64 q0 = qa ? 0ull : lo;
  u64 q1 = qa ? lo : hi;
  u64 q2 = qa ? hi : 0ull;
  u64 q3 = (u64)(((u32)sh) << 16) | (((u64)(u32)sl) << 32);
  u64 ra = h ? q2 : q0;
  u64 rb = h ? q3 : q1;
  u32x4 r;
  r.x = (u32)ra; r.y = (u32)(ra >> 32);
  r.z = (u32)rb; r.w = (u32)(rb >> 32);
  return r;
}

// ---------------------------------------------------------------------------
// expand_a: materialize A_packed (bf16, MFMA-fragment order, sk-major):
// chunk c = sk*512 + rbk (sk = kexp32-block 0..255, rbk = row16-block 0..511),
// 1KB each. Lane l of chunk holds row rbk*16+(l&15), kexp sk*32+(l>>4)*8..+7
// = half (l>>4)&1 of expand(x[row][2*sk + ((l>>4)>>1)]). Coalesced 1KB store
// per wave. 8.4M expandHalf total = 2x LESS VALU than the inline duplicated
// path, and it leaves the GEMM hot loop VALU-free.
// ---------------------------------------------------------------------------
__global__ void expand_a(const float* __restrict__ x, char* __restrict__ Ap) {
  const int tid = threadIdx.x;
  const int lane = tid & 63;
  const int wid = tid >> 6;
  const int c = blockIdx.x * 4 + wid;   // chunk id 0..131071
  const int rbk = c & 511;
  const int sk = c >> 9;
  const int row = rbk * 16 + (lane & 15);
  const int lkg = lane >> 4;
  const int dim = 2 * sk + (lkg >> 1);
  const int h = lkg & 1;
  float xv = x[(size_t)row * IN_DIM + dim];
  u32x4 r = expandHalf(xv, h);
  *(u32x4*)(Ap + (size_t)c * 1024 + lane * 16) = r;
}

// ---------------------------------------------------------------------------
// kan_gemm2: barrier-free, LDS-free K-loop (R12 skeleton, verified) with A
// from A_packed instead of in-register expansion. 8 waves = wm2 x wn2 x kt2,
// wave tile 64x64, acc[4][4]. Per step: 4 A-frag + 4 B-frag loads (1-step
// reg-dbuf prefetch), 16 MFMA. sk-major A layout -> fm = imm offsets
// (0/1024/2048/3072); step stride = uniform SGPR add. LDS only for the
// epilogue kt-reduction.
// ---------------------------------------------------------------------------
#define MM(AF, BV)                                                             \
  {                                                                            \
    __builtin_amdgcn_s_setprio(1);                                             \
    _Pragma("unroll")                                                          \
    for (int fm = 0; fm < 4; ++fm)                                             \
      _Pragma("unroll")                                                        \
      for (int fn = 0; fn < 4; ++fn)                                           \
        acc[fm][fn] = __builtin_amdgcn_mfma_f32_16x16x32_bf16(                 \
            __builtin_bit_cast(bf16x8, AF[fm]),                                \
            __builtin_bit_cast(bf16x8, BV[fn]), acc[fm][fn], 0, 0, 0);         \
    __builtin_amdgcn_s_setprio(0);                                             \
  }

__launch_bounds__(512, 2)
__global__ void kan_gemm2(const float* __restrict__ x,
                          const char* __restrict__ Ap,
                          const char* __restrict__ Bp,
                          float* __restrict__ out) {
  __shared__ __align__(16) char smem[67584];  // epilogue red: 128 x 132 f32

  const int tid = threadIdx.x;
  const int lane = tid & 63;
  const int wid = tid >> 6;
  const int kt = wid >> 2;             // K-split team (sk parity)
  const int wm = (wid >> 1) & 1, wn = wid & 1;
  const int lrow = lane & 15, lkg = lane >> 4;

  int s0 = blockIdx.x;
  int xcd = s0 & 7;
  int nb = xcd >> 1;                   // XCD pair owns one 2MB B panel in L2
  int mb = ((s0 >> 3) << 1) | (xcd & 1);  // 0..63

  const int rb = mb * 8 + wm * 4;      // rbk base for this wave's rows

  // A base: chunk(sk = s*2 + kt, rbk = rb + fm); fm -> imm offset fm*1024
  const char* abase = Ap + (((size_t)kt * 512 + rb) * 1024) + (size_t)lane * 16;
  // step stride in A: sk += 2  ->  +1 MB
  const char* bptr = Bp + (((size_t)(nb * 128) * 8 + wn * 4) * 2 + kt) * 1024 + (size_t)lane * 16;

  f32x4 acc[4][4];
#pragma unroll
  for (int i = 0; i < 4; ++i)
#pragma unroll
    for (int j = 0; j < 4; ++j) acc[i][j] = (f32x4){0.f, 0.f, 0.f, 0.f};

  u32x4 bA[4], bB[4], afA[4], afB[4];

  // prologue: A(0), B(0)
#pragma unroll
  for (int fm = 0; fm < 4; ++fm)
    afA[fm] = *(const u32x4*)(abase + fm * 1024);
#pragma unroll
  for (int fn = 0; fn < 4; ++fn)
    bA[fn] = *(const u32x4*)(bptr + fn * 2048);

  // S = current compute step; prefetch step S+1 (clamped) then MFMA(S).
#define STEP2(S, AFC, AFN, BCUR, BNXT)                                         \
  {                                                                            \
    int sl_ = (S) + 1 < 128 ? (S) + 1 : 127;                                   \
    const char* ap_ = abase + (size_t)sl_ * 1048576;                           \
    const char* bp_ = bptr + (size_t)sl_ * 16384;                              \
    _Pragma("unroll")                                                          \
    for (int fn = 0; fn < 4; ++fn)                                             \
      BNXT[fn] = *(const u32x4*)(bp_ + fn * 2048);                             \
    _Pragma("unroll")                                                          \
    for (int fm = 0; fm < 4; ++fm)                                             \
      AFN[fm] = *(const u32x4*)(ap_ + fm * 1024);                              \
    MM(AFC, BCUR)                                                              \
  }

#pragma unroll 1
  for (int s = 0; s < 128; s += 2) {
    STEP2(s, afA, afB, bA, bB)
    STEP2(s + 1, afB, afA, bB, bA)
  }

  __syncthreads();  // all waves done; smem safe to use

  // epilogue: deterministic kt-reduction via LDS (stride 132 floats), +x
  float* red = (float*)smem;
  if (kt == 1) {
#pragma unroll
    for (int fm = 0; fm < 4; ++fm)
#pragma unroll
      for (int fn = 0; fn < 4; ++fn) {
        int rr = wm * 64 + fm * 16 + lkg * 4;
        int cc = wn * 64 + fn * 16 + lrow;
#pragma unroll
        for (int r = 0; r < 4; ++r)
          red[(size_t)(rr + r) * 132 + cc] = acc[fm][fn][r];
      }
  }
  __syncthreads();
  if (kt == 0) {
#pragma unroll
    for (int fm = 0; fm < 4; ++fm)
#pragma unroll
      for (int fn = 0; fn < 4; ++fn) {
        int rr = wm * 64 + fm * 16 + lkg * 4;
        int cc = wn * 64 + fn * 16 + lrow;
        size_t gb = (size_t)(mb * 128 + rr) * IN_DIM + nb * 128 + cc;
#pragma unroll
        for (int r = 0; r < 4; ++r) {
          size_t off = gb + (size_t)r * IN_DIM;
          out[off] = acc[fm][fn][r] + red[(size_t)(rr + r) * 132 + cc] + x[off];
        }
      }
  }
}

// ---------------------------------------------------------------------------
// expandA (LDS-writing variant) + kan_gemm (R11, 89us) — mid-tier fallback
// when ws fits B_packed but not A_packed.
// ---------------------------------------------------------------------------
__device__ __forceinline__ void expandA(float xv, char* rb, u32 swz, u32 k0) {
  float xc = fminf(fmaxf(xv, -0.9999f), 0.9999f);
  float tp = __fmaf_rn(xc, 2.5f, 3.0f);
  float fj = floorf(tp);
  int jl = (int)fj;  // 0..5
  float u = tp - fj;
  float u2 = u * u, u3 = u2 * u;
  float vv = 1.0f - u;
  float b0 = vv * vv * vv * (1.0f / 6.0f);
  float b3 = u3 * (1.0f / 6.0f);
  float b1 = __fmaf_rn(0.5f, u3, __fmaf_rn(u2, -1.0f, 2.0f / 3.0f));
  float b2 = 1.0f - b0 - b1 - b3;
  float e = __expf(-xv);
  float sg = __fdividef(xv, 1.0f + e);
  u16 sh = bfr(sg);
  float shf = __builtin_bit_cast(float, ((u32)sh) << 16);
  u16 sl = bfr(sg - shf);
  u32 pk01 = (u32)bfr(b0) | ((u32)bfr(b1) << 16);
  u32 pk23 = (u32)bfr(b2) | ((u32)bfr(b3) << 16);
  u64 v = (u64)pk01 | (((u64)pk23) << 32);
  int sstart = jl + 2;       // 2..7
  int qa = sstart >> 2;
  int shn = (sstart & 3) << 4;
  u64 lo = v << shn;
  u64 hi = shn ? (v >> (64 - shn)) : 0ull;
  u64 q0 = qa ? 0ull : lo;
  u64 q1 = qa ? lo : hi;
  u64 q2 = qa ? hi : 0ull;
  u64 q3 = (u64)(((u32)sh) << 16) | (((u64)(u32)sl) << 32);
  u32x4 c0, c1;
  c0.x = (u32)q0; c0.y = (u32)(q0 >> 32); c0.z = (u32)q1; c0.w = (u32)(q1 >> 32);
  c1.x = (u32)q2; c1.y = (u32)(q2 >> 32); c1.z = (u32)q3; c1.w = (u32)(q3 >> 32);
  *(u32x4*)(rb + ((k0 ^ swz) << 4)) = c0;
  *(u32x4*)(rb + (((k0 + 1u) ^ swz) << 4)) = c1;
}

__launch_bounds__(768, 3)
__global__ void kan_gemm(const float* __restrict__ x,
                         const char* __restrict__ Bp,
                         float* __restrict__ out) {
  __shared__ __align__(16) char smem[131072];  // 2 x 64KB interval buffers

  const int tid = threadIdx.x;
  const int lane = tid & 63;
  const int wid = tid >> 6;
  const bool isC = (wid < 8);

  const int kt = wid >> 2;
  const int wm = (wid >> 1) & 1, wn = wid & 1;
  const int lrow = lane & 15, lkg = lane >> 4;

  int s0 = blockIdx.x;
  int xcd = s0 & 7;
  int nb = xcd >> 1;
  int mb = ((s0 >> 3) << 1) | (xcd & 1);

  const int te = tid & 255;
  const int erow = te >> 2;
  const int ad = te & 3;
  const u32 aswz = (u32)(erow & 7);
  const u32 ak0 = (u32)(ad * 2);
  const float* xpa = x + (size_t)(mb * 128 + erow) * IN_DIM + ad;
  const float* xpb = xpa + (size_t)64 * IN_DIM;

  const char* bptr = Bp + (((size_t)(nb * 128) * 8 + wn * 4) * 2 + kt) * 1024 + (size_t)lane * 16;

  f32x4 acc[4][4];
#pragma unroll
  for (int i = 0; i < 4; ++i)
#pragma unroll
    for (int j = 0; j < 4; ++j) acc[i][j] = (f32x4){0.f, 0.f, 0.f, 0.f};

  u32x4 bA[4], bB[4];
  char* ab0 = smem;
  char* ab1 = smem + 65536;

  float xc[8];
#pragma unroll
  for (int j = 0; j < 8; ++j) xc[j] = 0.f;

  if (isC) {
#pragma unroll
    for (int fn = 0; fn < 4; ++fn)
      bA[fn] = *(const u32x4*)(bptr + fn * 2048);
  } else {
    float xi[8];
#pragma unroll
    for (int k = 0; k < 4; ++k) { xi[2 * k] = xpa[4 * k]; xi[2 * k + 1] = xpb[4 * k]; }
#pragma unroll
    for (int k = 0; k < 4; ++k) {
      expandA(xi[2 * k],     ab0 + k * 16384 + erow * 128, aswz, ak0);
      expandA(xi[2 * k + 1], ab0 + k * 16384 + (erow + 64) * 128, aswz, ak0);
    }
#pragma unroll
    for (int k = 0; k < 4; ++k) { xc[2 * k] = xpa[16 + 4 * k]; xc[2 * k + 1] = xpb[16 + 4 * k]; }
  }
  __syncthreads();

  const u32 asl = (((u32)(kt * 4) | (u32)lkg) ^ (u32)(lrow & 7)) << 4;

#pragma unroll 1
  for (int iv = 0; iv < 32; ++iv) {
    if (isC) {
      const char* rbuf = (iv & 1) ? ab1 : ab0;
      const char* arb = rbuf + (wm * 64 + lrow) * 128;
      const int S = iv * 4;
      u32x4 af0[4], af1[4];
#pragma unroll
      for (int fm = 0; fm < 4; ++fm)
        af0[fm] = *(const u32x4*)(arb + fm * 2048 + asl);
#pragma unroll
      for (int fm = 0; fm < 4; ++fm)
        af1[fm] = *(const u32x4*)(arb + 16384 + fm * 2048 + asl);
#pragma unroll
      for (int fn = 0; fn < 4; ++fn)
        bB[fn] = *(const u32x4*)(bptr + (size_t)(S + 1) * 16384 + fn * 2048);
      MM(af0, bA)
#pragma unroll
      for (int fm = 0; fm < 4; ++fm)
        af0[fm] = *(const u32x4*)(arb + 2 * 16384 + fm * 2048 + asl);
#pragma unroll
      for (int fn = 0; fn < 4; ++fn)
        bA[fn] = *(const u32x4*)(bptr + (size_t)(S + 2) * 16384 + fn * 2048);
      MM(af1, bB)
#pragma unroll
      for (int fm = 0; fm < 4; ++fm)
        af1[fm] = *(const u32x4*)(arb + 3 * 16384 + fm * 2048 + asl);
#pragma unroll
      for (int fn = 0; fn < 4; ++fn)
        bB[fn] = *(const u32x4*)(bptr + (size_t)(S + 3) * 16384 + fn * 2048);
      MM(af0, bA)
      {
        int sn = (S + 4 < 128) ? (S + 4) : 127;
#pragma unroll
        for (int fn = 0; fn < 4; ++fn)
          bA[fn] = *(const u32x4*)(bptr + (size_t)sn * 16384 + fn * 2048);
      }
      MM(af1, bB)
    } else {
      if (iv + 1 < 32) {
        char* wb = (iv & 1) ? ab0 : ab1;
#pragma unroll
        for (int k = 0; k < 4; ++k) {
          expandA(xc[2 * k],     wb + k * 16384 + erow * 128, aswz, ak0);
          expandA(xc[2 * k + 1], wb + k * 16384 + (erow + 64) * 128, aswz, ak0);
        }
      }
      {
        int v2 = (iv + 2 < 32) ? (iv + 2) : 31;
        float xn[8];
#pragma unroll
        for (int k = 0; k < 4; ++k) {
          xn[2 * k]     = xpa[v2 * 16 + 4 * k];
          xn[2 * k + 1] = xpb[v2 * 16 + 4 * k];
        }
#pragma unroll
        for (int j = 0; j < 8; ++j) xc[j] = xn[j];
      }
      asm volatile("s_waitcnt lgkmcnt(0)" ::: "memory");
    }
    __builtin_amdgcn_s_barrier();
  }

  __syncthreads();

  float* red = (float*)smem;
  if (isC && kt == 1) {
#pragma unroll
    for (int fm = 0; fm < 4; ++fm)
#pragma unroll
      for (int fn = 0; fn < 4; ++fn) {
        int rr = wm * 64 + fm * 16 + lkg * 4;
        int cc = wn * 64 + fn * 16 + lrow;
#pragma unroll
        for (int r = 0; r < 4; ++r)
          red[(size_t)(rr + r) * 132 + cc] = acc[fm][fn][r];
      }
  }
  __syncthreads();
  if (isC && kt == 0) {
#pragma unroll
    for (int fm = 0; fm < 4; ++fm)
#pragma unroll
      for (int fn = 0; fn < 4; ++fn) {
        int rr = wm * 64 + fm * 16 + lkg * 4;
        int cc = wn * 64 + fn * 16 + lrow;
        size_t gb = (size_t)(mb * 128 + rr) * IN_DIM + nb * 128 + cc;
#pragma unroll
        for (int r = 0; r < 4; ++r) {
          size_t off = gb + (size_t)r * IN_DIM;
          out[off] = acc[fm][fn][r] + red[(size_t)(rr + r) * 132 + cc] + x[off];
        }
      }
  }
}

// ---------------------------------------------------------------------------
// Fallback (round-1 kernel) if ws too small for B_packed (8MB)
// ---------------------------------------------------------------------------
__device__ __forceinline__ void st_b16(char* rb, u32 swz, u32 k0, int c, u16 v) {
  u32 uc = (u32)c;
  u32 byte = (((k0 + (uc >> 3)) ^ swz) << 4) | ((uc & 7u) << 1);
  *(u16*)(rb + byte) = v;
}

__device__ __forceinline__ void stage_a_fb(char* aT, int row, int d, float xv) {
  char* rb = aT + row * 128;
  u32 swz = (u32)(row & 7);
  float xc = fminf(fmaxf(xv, -0.9999f), 0.9999f);
  float tp = __fmaf_rn(xc, 2.5f, 3.0f);
  float fj = floorf(tp);
  int jl = (int)fj;
  float u = tp - fj;
  float u2 = u * u, u3 = u2 * u;
  float vv = 1.0f - u;
  float b0 = vv * vv * vv * (1.0f / 6.0f);
  float b3 = u3 * (1.0f / 6.0f);
  float b1 = __fmaf_rn(0.5f, u3, __fmaf_rn(u2, -1.0f, 2.0f / 3.0f));
  float b2 = 1.0f - b0 - b1 - b3;
  float e = __expf(-xv);
  float sg = __fdividef(xv, 1.0f + e);
  u16 sh = f2bf(sg);
  float shf = __builtin_bit_cast(float, ((u32)sh) << 16);
  u16 slo = f2bf(sg - shf);
  u32 k0 = (u32)d * 2u;
  u32x4 z = {0u, 0u, 0u, 0u};
  *(u32x4*)(rb + ((k0 ^ swz) << 4)) = z;
  u32x4 z2 = {0u, 0u, ((u32)sh) << 16, (u32)slo};
  *(u32x4*)(rb + (((k0 + 1u) ^ swz) << 4)) = z2;
  st_b16(rb, swz, k0, jl + 2, f2bf(b0));
  st_b16(rb, swz, k0, jl + 3, f2bf(b1));
  st_b16(rb, swz, k0, jl + 4, f2bf(b2));
  st_b16(rb, swz, k0, jl + 5, f2bf(b3));
}

__launch_bounds__(512, 2)
__global__ void kan_fused(const float* __restrict__ x,
                          const float* __restrict__ coeffs,
                          const float* __restrict__ bw,
                          float* __restrict__ out) {
  __shared__ __align__(16) char smem[65536];
  const int tid = threadIdx.x;
  const int lane = tid & 63;
  const int wid = tid >> 6;
  const int team = wid >> 2;
  const int wm = (wid >> 1) & 1;
  const int wn = wid & 1;
  const int m0 = wm * 64, n0 = wn * 64;
  const int lrow = lane & 15;
  const int lkg = lane >> 4;
  int s = blockIdx.x;
  int xcd = s & 7;
  int nb = xcd >> 1;
  int mb = (s >> 3) | ((xcd & 1) << 5);
  const int t = tid & 255;
  const int arow = t >> 1;
  const int h = t & 1;
  char* aT = smem + team * 16384;
  char* bT = smem + 32768 + team * 16384;
  const int dim0 = team * 256;
  const float* xptr = x + (size_t)(mb * 128 + arow) * IN_DIM + dim0 + 2 * h;
  const float* cptr = coeffs + ((size_t)((nb * 128 + arow) * IN_DIM) + dim0) * 13 + 26 * h;
  const float* wptr = bw + (size_t)(nb * 128 + arow) * IN_DIM + dim0 + 2 * h;
  f32x4 acc[4][4];
#pragma unroll
  for (int i = 0; i < 4; ++i)
#pragma unroll
    for (int j = 0; j < 4; ++j) acc[i][j] = (f32x4){0.f, 0.f, 0.f, 0.f};
  float2 xv, wv;
  float2 cv0, cv1, cv2, cv3, cv4, cv5, cv6, cv7, cv8, cv9, cv10, cv11, cv12;
#define PREFETCH(STP)                                                     \
  {                                                                       \
    const float* cp_ = cptr + (STP) * 52;                                 \
    xv = *(const float2*)(xptr + (STP) * 4);                              \
    wv = *(const float2*)(wptr + (STP) * 4);                              \
    cv0 = *(const float2*)(cp_ + 0);   cv1 = *(const float2*)(cp_ + 2);   \
    cv2 = *(const float2*)(cp_ + 4);   cv3 = *(const float2*)(cp_ + 6);   \
    cv4 = *(const float2*)(cp_ + 8);   cv5 = *(const float2*)(cp_ + 10);  \
    cv6 = *(const float2*)(cp_ + 12);  cv7 = *(const float2*)(cp_ + 14);  \
    cv8 = *(const float2*)(cp_ + 16);  cv9 = *(const float2*)(cp_ + 18);  \
    cv10 = *(const float2*)(cp_ + 20); cv11 = *(const float2*)(cp_ + 22); \
    cv12 = *(const float2*)(cp_ + 24);                                    \
  }
  PREFETCH(0)
  for (int st = 0; st < 64; ++st) {
    stage_a_fb(aT, arow, 2 * h + 0, xv.x);
    stage_a_fb(aT, arow, 2 * h + 1, xv.y);
    {
      char* rb = bT + arow * 128;
      u32 swz = (u32)(arow & 7);
      u32 k0 = (u32)(2 * h) * 2u;
      u32x4 lo, hi;
      lo.x = pk2(cv0.x, cv0.y); lo.y = pk2(cv1.x, cv1.y);
      lo.z = pk2(cv2.x, cv2.y); lo.w = pk2(cv3.x, cv3.y);
      hi.x = pk2(cv4.x, cv4.y); hi.y = pk2(cv5.x, cv5.y);
      {
        u16 wb = f2bf(wv.x);
        hi.z = (u32)f2bf(cv6.x) | ((u32)wb << 16);
        hi.w = (u32)wb;
      }
      *(u32x4*)(rb + ((k0 ^ swz) << 4)) = lo;
      *(u32x4*)(rb + (((k0 + 1u) ^ swz) << 4)) = hi;
      lo.x = pk2(cv6.y, cv7.x);  lo.y = pk2(cv7.y, cv8.x);
      lo.z = pk2(cv8.y, cv9.x);  lo.w = pk2(cv9.y, cv10.x);
      hi.x = pk2(cv10.y, cv11.x); hi.y = pk2(cv11.y, cv12.x);
      {
        u16 wb = f2bf(wv.y);
        hi.z = (u32)f2bf(cv12.y) | ((u32)wb << 16);
        hi.w = (u32)wb;
      }
      *(u32x4*)(rb + (((k0 + 2u) ^ swz) << 4)) = lo;
      *(u32x4*)(rb + (((k0 + 3u) ^ swz) << 4)) = hi;
    }
    __syncthreads();
    if (st != 63) { PREFETCH(st + 1) }
    {
      const char* arb = aT + (m0 + lrow) * 128;
      const char* brb = bT + (n0 + lrow) * 128;
      u32 rsw = (u32)(lrow & 7);
#pragma unroll
      for (int ks = 0; ks < 2; ++ks) {
        u32 sl2 = (((u32)(ks * 4) | (u32)lkg) ^ rsw) << 4;
        bf16x8 af[4], bfr2[4];
#pragma unroll
        for (int fm = 0; fm < 4; ++fm)
          af[fm] = __builtin_bit_cast(bf16x8, *(const u32x4*)(arb + fm * 2048 + sl2));
#pragma unroll
        for (int fn = 0; fn < 4; ++fn)
          bfr2[fn] = __builtin_bit_cast(bf16x8, *(const u32x4*)(brb + fn * 2048 + sl2));
#pragma unroll
        for (int fm = 0; fm < 4; ++fm)
#pragma unroll
          for (int fn = 0; fn < 4; ++fn)
            acc[fm][fn] = __builtin_amdgcn_mfma_f32_16x16x32_bf16(
                af[fm], bfr2[fn], acc[fm][fn], 0, 0, 0);
      }
    }
    __syncthreads();
  }
  float* red = (float*)smem;
  if (team == 1) {
#pragma unroll
    for (int fm = 0; fm < 4; ++fm)
#pragma unroll
      for (int fn = 0; fn < 4; ++fn) {
        int rr = m0 + fm * 16 + lkg * 4;
        int cc = n0 + fn * 16 + lrow;
#pragma unroll
        for (int r = 0; r < 4; ++r) red[(rr + r) * 128 + cc] = acc[fm][fn][r];
      }
  }
  __syncthreads();
  if (team == 0) {
#pragma unroll
    for (int fm = 0; fm < 4; ++fm)
#pragma unroll
      for (int fn = 0; fn < 4; ++fn) {
        int rr = m0 + fm * 16 + lkg * 4;
        int ccol = n0 + fn * 16 + lrow;
        int grow = mb * 128 + rr;
        int gcol = nb * 128 + ccol;
#pragma unroll
        for (int r = 0; r < 4; ++r) {
          float v = acc[fm][fn][r] + red[(rr + r) * 128 + ccol] +
                    x[(size_t)(grow + r) * IN_DIM + gcol];
          out[(size_t)(grow + r) * IN_DIM + gcol] = v;
        }
      }
  }
}

extern "C" void kernel_launch(void* const* d_in, const int* in_sizes, int n_in,
                              void* d_out, int out_size, void* d_ws, size_t ws_size,
                              hipStream_t stream) {
  const float* x = (const float*)d_in[0];
  const float* coeffs = (const float*)d_in[1];
  const float* bw = (const float*)d_in[2];
  float* out = (float*)d_out;
  const size_t B_BYTES = (size_t)8 << 20;     // 8 MB B_packed
  const size_t A_BYTES = (size_t)128 << 20;   // 128 MB A_packed
  if (ws_size >= B_BYTES + A_BYTES) {
    char* Bp = (char*)d_ws;
    char* Ap = (char*)d_ws + B_BYTES;
    hipLaunchKernelGGL(pack_b, dim3(1024), dim3(256), 0, stream, coeffs, bw, Bp);
    hipLaunchKernelGGL(expand_a, dim3(32768), dim3(256), 0, stream, x, Ap);
    hipLaunchKernelGGL(kan_gemm2, dim3(256), dim3(512), 0, stream, x, Ap, Bp, out);
  } else if (ws_size >= B_BYTES) {
    char* Bp = (char*)d_ws;
    hipLaunchKernelGGL(pack_b, dim3(1024), dim3(256), 0, stream, coeffs, bw, Bp);
    hipLaunchKernelGGL(kan_gemm, dim3(256), dim3(768), 0, stream, x, Bp, out);
  } else {
    hipLaunchKernelGGL(kan_fused, dim3(256), dim3(512), 0, stream, x, coeffs, bw, out);
  }
}